// Round 1
// 513.614 us; speedup vs baseline: 1.1353x; 1.1353x over previous
//
#include <hip/hip_runtime.h>

// out[m][n] = sum_k X[m][k] * Wq[n][k] * scale[n] + bias[n]
// M=8192, N=4096, K=4096. X fp32 [M][K]; Wq int32 ternary [N][K];
// scale fp32 [N]; bias fp32 [N]; Out fp32 [M][N].
//
// Round 4: 256x256 tile, 8-wave (2Mx4N), BK=64, 8-phase K-pair schedule with
// counted s_waitcnt vmcnt(4) (never 0 in steady state), setprio(1) around MFMA
// clusters, XOR-swizzled LDS (conflict-free ds_read_b128), XCD-aware block
// swizzle. Staging discipline (derived, race-free):
//   tile t ph0: stage A-half0 of t+1  (buf^1 A region dead since end of t-1)
//   tile t ph1: stage A-half1 of t+1
//   tile t ph2: stage B-half0 of t+2  (buf B region dead after t's ph0)
//   tile t ph3: stage B-half1 of t+2, then vmcnt(4) -> tile t+1 fully landed
// Fallback to round-1 fused kernel if ws_size is too small.

#define MDIM 8192
#define NDIM 4096
#define KDIM 4096
#define NT   64      // K tiles of 64

typedef __bf16 bf16x8 __attribute__((ext_vector_type(8)));
typedef float f32x4 __attribute__((ext_vector_type(4)));

#define BAR() asm volatile("s_barrier" ::: "memory")

__device__ __forceinline__ unsigned f2bf_pack(float lo, float hi) {
    unsigned a = __float_as_uint(lo);
    unsigned b = __float_as_uint(hi);
    a += 0x7FFFu + ((a >> 16) & 1u);
    b += 0x7FFFu + ((b >> 16) & 1u);
    return (a >> 16) | (b & 0xFFFF0000u);
}

__device__ __forceinline__ unsigned w2bf_pack(int lo, int hi) {
    unsigned a = __float_as_uint((float)lo) >> 16;
    unsigned b = __float_as_uint((float)hi) & 0xFFFF0000u;
    return a | b;
}

__device__ __forceinline__ void async_load16(const void* gptr, void* lptr) {
    __builtin_amdgcn_global_load_lds(
        (const __attribute__((address_space(1))) void*)gptr,
        (__attribute__((address_space(3))) void*)lptr, 16, 0, 0);
}

// ---------------- fused conversion pass ----------------
#define XGROUPS ((MDIM * (size_t)KDIM) / 8)   // 4M threads for X
#define WGROUPS ((NDIM * (size_t)KDIM) / 8)   // 2M threads for W

__global__ void convert_all(const float* __restrict__ X, const int* __restrict__ Wq,
                            uint4* __restrict__ Xb, uint4* __restrict__ Wb) {
    const size_t gid = (size_t)blockIdx.x * blockDim.x + threadIdx.x;
    if (gid < XGROUPS) {
        const f32x4 a = ((const f32x4*)X)[2 * gid];
        const f32x4 b = ((const f32x4*)X)[2 * gid + 1];
        Xb[gid] = make_uint4(f2bf_pack(a.x, a.y), f2bf_pack(a.z, a.w),
                             f2bf_pack(b.x, b.y), f2bf_pack(b.z, b.w));
    } else {
        const size_t wi = gid - XGROUPS;
        const int4 a = ((const int4*)Wq)[2 * wi];
        const int4 b = ((const int4*)Wq)[2 * wi + 1];
        Wb[wi] = make_uint4(w2bf_pack(a.x, a.y), w2bf_pack(a.z, a.w),
                            w2bf_pack(b.x, b.y), w2bf_pack(b.z, b.w));
    }
}

// ---------------- main GEMM: 256x256 tile, 8-phase schedule ----------------
// LDS: As/Bs = [buf(2)][half(2)][128 rows][64 bf16]; 128 B/row; data chunk c of
// row r stored at LDS chunk c^(r&7) via pre-swizzled global source address.

#define RDA(b_, P_, mt_, kh_) (*(const bf16x8*)((const char*)As + (b_)*32768 + \
        (P_)*4096 + (mt_)*2048 + ((kh_) ? aB1 : aB0)))
#define RDB(b_, nt_, kh_)     (*(const bf16x8*)((const char*)Bs + (b_)*32768 + \
        (nt_)*2048 + ((kh_) ? bB1 : bB0)))

__global__ __launch_bounds__(512)
void gemm_bf16_8ph(const unsigned short* __restrict__ Xb,
                   const unsigned short* __restrict__ Wb,
                   const float* __restrict__ scale,
                   const float* __restrict__ bias,
                   float* __restrict__ Out) {
    __shared__ unsigned short As[2 * 2 * 128 * 64];  // 64 KiB
    __shared__ unsigned short Bs[2 * 2 * 128 * 64];  // 64 KiB

    const int tid  = threadIdx.x;
    const int lane = tid & 63;
    const int wave = tid >> 6;       // 0..7
    const int wm   = wave >> 2;      // 0..1  (M half)
    const int wn   = wave & 3;       // 0..3  (N quarter)
    const int quad = lane >> 4;
    const int l16  = lane & 15;
    const int lr   = lane >> 3;      // staging row-in-group
    const int cc   = (lane & 7) ^ lr;  // pre-swizzled source chunk

    // XCD-aware swizzle: 512 blocks, 8 XCDs, 64 consecutive per XCD
    int lid = blockIdx.y * 16 + blockIdx.x;
    lid = (lid & 7) * 64 + (lid >> 3);
    const int n0 = (lid & 15) << 8;  // 16 N-tiles
    const int m0 = (lid >> 4) << 8;  // 32 M-tiles

    // staging global pointers: [half][issue]
    const unsigned short* pA[2][2];
    const unsigned short* pB[2][2];
#pragma unroll
    for (int h = 0; h < 2; ++h)
#pragma unroll
        for (int j = 0; j < 2; ++j) {
            pA[h][j] = Xb + (size_t)(m0 + h * 128 + j * 64 + wave * 8 + lr) * KDIM + cc * 8;
            pB[h][j] = Wb + (size_t)(n0 + h * 128 + j * 64 + wave * 8 + lr) * KDIM + cc * 8;
        }

    f32x4 acc[8][4];
#pragma unroll
    for (int i = 0; i < 8; ++i)
#pragma unroll
        for (int j = 0; j < 4; ++j)
            acc[i][j] = (f32x4){0.f, 0.f, 0.f, 0.f};

    // ds_read bases: row = <const> + l16, chunk = (kh*4+quad) ^ (l16&7)
    const int aoff = l16 * 128 + ((quad ^ (l16 & 7)) << 4);
    const int aB0  = (wm << 14) + aoff;          // kh=0
    const int aB1  = aB0 ^ 64;                   // kh=1 (chunk ^4)
    const int bB0  = ((wn >> 1) << 14) + ((wn & 1) << 13) + aoff;
    const int bB1  = bB0 ^ 64;

    auto stageA = [&](int t, int h, int b) {
        char* d = (char*)As + ((b * 2 + h) << 14) + wave * 1024;
        async_load16(pA[h][0] + (size_t)t * 64, d);
        async_load16(pA[h][1] + (size_t)t * 64, d + 8192);
    };
    auto stageB = [&](int t, int h, int b) {
        char* d = (char*)Bs + ((b * 2 + h) << 14) + wave * 1024;
        async_load16(pB[h][0] + (size_t)t * 64, d);
        async_load16(pB[h][1] + (size_t)t * 64, d + 8192);
    };

    auto tile = [&](int t, int b) {
        bf16x8 bfr[4][2];
        {   // ---- phase 0: compute m-quarter 0, read all B frags ----
            bf16x8 af[2][2];
#pragma unroll
            for (int mt = 0; mt < 2; ++mt) {
                af[mt][0] = RDA(b, 0, mt, 0);
                af[mt][1] = RDA(b, 0, mt, 1);
            }
#pragma unroll
            for (int nt = 0; nt < 4; ++nt) {
                bfr[nt][0] = RDB(b, nt, 0);
                bfr[nt][1] = RDB(b, nt, 1);
            }
            if (t + 1 < NT) stageA(t + 1, 0, b ^ 1);
            BAR();
            __builtin_amdgcn_s_setprio(1);
#pragma unroll
            for (int kh = 0; kh < 2; ++kh)
#pragma unroll
                for (int mt = 0; mt < 2; ++mt)
#pragma unroll
                    for (int nt = 0; nt < 4; ++nt)
                        acc[mt][nt] = __builtin_amdgcn_mfma_f32_16x16x32_bf16(
                            af[mt][kh], bfr[nt][kh], acc[mt][nt], 0, 0, 0);
            __builtin_amdgcn_s_setprio(0);
            BAR();
        }
        {   // ---- phase 1: m-quarter 1 ----
            bf16x8 af[2][2];
#pragma unroll
            for (int mt = 0; mt < 2; ++mt) {
                af[mt][0] = RDA(b, 1, mt, 0);
                af[mt][1] = RDA(b, 1, mt, 1);
            }
            if (t + 1 < NT) stageA(t + 1, 1, b ^ 1);
            BAR();
            __builtin_amdgcn_s_setprio(1);
#pragma unroll
            for (int kh = 0; kh < 2; ++kh)
#pragma unroll
                for (int mt = 0; mt < 2; ++mt)
#pragma unroll
                    for (int nt = 0; nt < 4; ++nt)
                        acc[2 + mt][nt] = __builtin_amdgcn_mfma_f32_16x16x32_bf16(
                            af[mt][kh], bfr[nt][kh], acc[2 + mt][nt], 0, 0, 0);
            __builtin_amdgcn_s_setprio(0);
            BAR();
        }
        {   // ---- phase 2: m-quarter 2 ----
            bf16x8 af[2][2];
#pragma unroll
            for (int mt = 0; mt < 2; ++mt) {
                af[mt][0] = RDA(b, 2, mt, 0);
                af[mt][1] = RDA(b, 2, mt, 1);
            }
            if (t + 2 < NT) stageB(t + 2, 0, b);
            BAR();
            __builtin_amdgcn_s_setprio(1);
#pragma unroll
            for (int kh = 0; kh < 2; ++kh)
#pragma unroll
                for (int mt = 0; mt < 2; ++mt)
#pragma unroll
                    for (int nt = 0; nt < 4; ++nt)
                        acc[4 + mt][nt] = __builtin_amdgcn_mfma_f32_16x16x32_bf16(
                            af[mt][kh], bfr[nt][kh], acc[4 + mt][nt], 0, 0, 0);
            __builtin_amdgcn_s_setprio(0);
            BAR();
        }
        {   // ---- phase 3: m-quarter 3, counted vmcnt ----
            bf16x8 af[2][2];
#pragma unroll
            for (int mt = 0; mt < 2; ++mt) {
                af[mt][0] = RDA(b, 3, mt, 0);
                af[mt][1] = RDA(b, 3, mt, 1);
            }
            if (t + 2 < NT) stageB(t + 2, 1, b);
            if (t < NT - 2) asm volatile("s_waitcnt vmcnt(4)" ::: "memory");
            else            asm volatile("s_waitcnt vmcnt(0)" ::: "memory");
            BAR();
            __builtin_amdgcn_s_setprio(1);
#pragma unroll
            for (int kh = 0; kh < 2; ++kh)
#pragma unroll
                for (int mt = 0; mt < 2; ++mt)
#pragma unroll
                    for (int nt = 0; nt < 4; ++nt)
                        acc[6 + mt][nt] = __builtin_amdgcn_mfma_f32_16x16x32_bf16(
                            af[mt][kh], bfr[nt][kh], acc[6 + mt][nt], 0, 0, 0);
            __builtin_amdgcn_s_setprio(0);
            BAR();
        }
    };

    // prologue: tile0 (all 4 halves) + tile1 B halves; wait tile0 landed
    stageA(0, 0, 0); stageA(0, 1, 0); stageB(0, 0, 0); stageB(0, 1, 0);
    stageB(1, 0, 1); stageB(1, 1, 1);
    asm volatile("s_waitcnt vmcnt(4)" ::: "memory");
    BAR();

    for (int tt = 0; tt < NT; tt += 2) {
        tile(tt, 0);
        tile(tt + 1, 1);
    }

    // epilogue: C/D layout col = lane&15, row = quad*4 + r
#pragma unroll
    for (int nt = 0; nt < 4; ++nt) {
        const int n = n0 + wn * 64 + nt * 16 + l16;
        const float sc = scale[n];
        const float bi = bias[n];
#pragma unroll
        for (int mf = 0; mf < 8; ++mf) {
#pragma unroll
            for (int r = 0; r < 4; ++r) {
                const int m = m0 + wm * 128 + mf * 16 + quad * 4 + r;
                Out[(size_t)m * NDIM + n] = acc[mf][nt][r] * sc + bi;
            }
        }
    }
}

#undef RDA
#undef RDB

// ---------------- round-1 fused fallback (if ws too small) ----------------

#define BM 128
#define BN 128
#define BK 64
#define LDSS 72

__global__ __launch_bounds__(256, 2)
void ternary_gemm_fused(const float* __restrict__ X, const int* __restrict__ Wq,
                        const float* __restrict__ scale, const float* __restrict__ bias,
                        float* __restrict__ Out) {
    __shared__ unsigned short As[BM * LDSS];
    __shared__ unsigned short Bs[BN * LDSS];

    const int tid  = threadIdx.x;
    const int lane = tid & 63;
    const int wave = tid >> 6;
    const int quad = lane >> 4;
    const int l16  = lane & 15;
    const int wm   = (wave >> 1) * 64;
    const int wn   = (wave & 1) * 64;

    const int m0 = blockIdx.y * BM;
    const int n0 = blockIdx.x * BN;

    const int srow = tid >> 4;
    const int scol = (tid & 15) * 4;

    const float* Aptr = X  + (size_t)(m0 + srow) * KDIM + scol;
    const int*   Bptr = Wq + (size_t)(n0 + srow) * KDIM + scol;

    f32x4 acc[4][4];
#pragma unroll
    for (int i = 0; i < 4; i++)
#pragma unroll
        for (int j = 0; j < 4; j++)
            acc[i][j] = (f32x4){0.f, 0.f, 0.f, 0.f};

    for (int kt = 0; kt < KDIM; kt += BK) {
        uint2 apk[8], bpk[8];
#pragma unroll
        for (int j = 0; j < 8; j++) {
            const f32x4 av = *(const f32x4*)(Aptr + (size_t)j * 16 * KDIM + kt);
            apk[j].x = f2bf_pack(av.x, av.y);
            apk[j].y = f2bf_pack(av.z, av.w);
        }
#pragma unroll
        for (int j = 0; j < 8; j++) {
            const int4 bv = *(const int4*)(Bptr + (size_t)j * 16 * KDIM + kt);
            bpk[j].x = w2bf_pack(bv.x, bv.y);
            bpk[j].y = w2bf_pack(bv.z, bv.w);
        }
        __syncthreads();
#pragma unroll
        for (int j = 0; j < 8; j++) {
            *(uint2*)&As[(srow + j * 16) * LDSS + scol] = apk[j];
            *(uint2*)&Bs[(srow + j * 16) * LDSS + scol] = bpk[j];
        }
        __syncthreads();

#pragma unroll
        for (int h = 0; h < 2; h++) {
            bf16x8 af[4], bf[4];
#pragma unroll
            for (int mt = 0; mt < 4; mt++)
                af[mt] = *(const bf16x8*)&As[(wm + mt * 16 + l16) * LDSS + h * 32 + quad * 8];
#pragma unroll
            for (int nt = 0; nt < 4; nt++)
                bf[nt] = *(const bf16x8*)&Bs[(wn + nt * 16 + l16) * LDSS + h * 32 + quad * 8];
#pragma unroll
            for (int mt = 0; mt < 4; mt++)
#pragma unroll
                for (int nt = 0; nt < 4; nt++)
                    acc[mt][nt] = __builtin_amdgcn_mfma_f32_16x16x32_bf16(
                        af[mt], bf[nt], acc[mt][nt], 0, 0, 0);
        }
    }

#pragma unroll
    for (int nt = 0; nt < 4; nt++) {
        const int n = n0 + wn + nt * 16 + l16;
        const float sc = scale[n];
        const float bi = bias[n];
#pragma unroll
        for (int mt = 0; mt < 4; mt++) {
#pragma unroll
            for (int r = 0; r < 4; r++) {
                const int m = m0 + wm + mt * 16 + quad * 4 + r;
                Out[(size_t)m * NDIM + n] = acc[mt][nt][r] * sc + bi;
            }
        }
    }
}

extern "C" void kernel_launch(void* const* d_in, const int* in_sizes, int n_in,
                              void* d_out, int out_size, void* d_ws, size_t ws_size,
                              hipStream_t stream) {
    const float* x     = (const float*)d_in[0];
    const int*   wq    = (const int*)d_in[1];
    const float* scale = (const float*)d_in[2];
    const float* bias  = (const float*)d_in[3];
    float* out = (float*)d_out;

    const size_t xb_bytes = (size_t)MDIM * KDIM * 2;  // 64 MiB
    const size_t wb_bytes = (size_t)NDIM * KDIM * 2;  // 32 MiB

    if (ws_size >= xb_bytes + wb_bytes) {
        unsigned short* Xb = (unsigned short*)d_ws;
        unsigned short* Wb = (unsigned short*)((char*)d_ws + xb_bytes);

        const size_t total_groups = XGROUPS + WGROUPS;  // 6M threads
        convert_all<<<(unsigned)(total_groups / 256), 256, 0, stream>>>(
            x, wq, (uint4*)Xb, (uint4*)Wb);

        dim3 grid(NDIM / 256, MDIM / 256);  // (16, 32)
        gemm_bf16_8ph<<<grid, dim3(512), 0, stream>>>(Xb, Wb, scale, bias, out);
    } else {
        dim3 grid(NDIM / BN, MDIM / BM);
        ternary_gemm_fused<<<grid, dim3(256), 0, stream>>>(x, wq, scale, bias, out);
    }
}

// Round 2
// 508.784 us; speedup vs baseline: 1.1461x; 1.0095x over previous
//
#include <hip/hip_runtime.h>

// out[m][n] = sum_k X[m][k] * Wq[n][k] * scale[n] + bias[n]
// M=8192, N=4096, K=4096. X fp32 [M][K]; Wq int32 ternary [N][K];
// scale fp32 [N]; bias fp32 [N]; Out fp32 [M][N].
//
// Round 5: convert pass rewritten as grid-strided dense-access streaming
// kernel (2048 blocks, 16B dense loads per lane, 8B dense stores) — the old
// version ran at ~1.2 TB/s due to 32B-lane-strided loads + 24576 one-shot
// blocks. GEMM (256x256 8-phase counted-vmcnt) byte-identical to round 4.
// Fallback to round-1 fused kernel if ws_size is too small.

#define MDIM 8192
#define NDIM 4096
#define KDIM 4096
#define NT   64      // K tiles of 64

typedef __bf16 bf16x8 __attribute__((ext_vector_type(8)));
typedef float f32x4 __attribute__((ext_vector_type(4)));

#define BAR() asm volatile("s_barrier" ::: "memory")

__device__ __forceinline__ unsigned f2bf_pack(float lo, float hi) {
    unsigned a = __float_as_uint(lo);
    unsigned b = __float_as_uint(hi);
    a += 0x7FFFu + ((a >> 16) & 1u);
    b += 0x7FFFu + ((b >> 16) & 1u);
    return (a >> 16) | (b & 0xFFFF0000u);
}

__device__ __forceinline__ unsigned w2bf_pack(int lo, int hi) {
    unsigned a = __float_as_uint((float)lo) >> 16;
    unsigned b = __float_as_uint((float)hi) & 0xFFFF0000u;
    return a | b;
}

__device__ __forceinline__ void async_load16(const void* gptr, void* lptr) {
    __builtin_amdgcn_global_load_lds(
        (const __attribute__((address_space(1))) void*)gptr,
        (__attribute__((address_space(3))) void*)lptr, 16, 0, 0);
}

// ---------------- conversion pass: dense streaming, grid-stride ----------------
// X: 8 Mi float4 -> uint2 (bf16x4). W: 4 Mi int4 -> uint2. Lane loads are
// 16B DENSE (lane i reads base + 16*i); stores 8B dense.

#define XG4 ((size_t)MDIM * KDIM / 4)   // 8 Mi groups
#define WG4 ((size_t)NDIM * KDIM / 4)   // 4 Mi groups
#define CVT_BLOCKS 2048

__global__ __launch_bounds__(256)
void convert_all(const float* __restrict__ X, const int* __restrict__ Wq,
                 uint2* __restrict__ Xb, uint2* __restrict__ Wb) {
    const size_t t0 = (size_t)blockIdx.x * blockDim.x + threadIdx.x;
    const size_t stride = (size_t)gridDim.x * blockDim.x;   // 512K
#pragma unroll 2
    for (size_t g = t0; g < XG4; g += stride) {
        const f32x4 a = ((const f32x4*)X)[g];
        Xb[g] = make_uint2(f2bf_pack(a.x, a.y), f2bf_pack(a.z, a.w));
    }
#pragma unroll 2
    for (size_t g = t0; g < WG4; g += stride) {
        const int4 a = ((const int4*)Wq)[g];
        Wb[g] = make_uint2(w2bf_pack(a.x, a.y), w2bf_pack(a.z, a.w));
    }
}

// ---------------- main GEMM: 256x256 tile, 8-phase schedule ----------------
// LDS: As/Bs = [buf(2)][half(2)][128 rows][64 bf16]; 128 B/row; data chunk c of
// row r stored at LDS chunk c^(r&7) via pre-swizzled global source address.

#define RDA(b_, P_, mt_, kh_) (*(const bf16x8*)((const char*)As + (b_)*32768 + \
        (P_)*4096 + (mt_)*2048 + ((kh_) ? aB1 : aB0)))
#define RDB(b_, nt_, kh_)     (*(const bf16x8*)((const char*)Bs + (b_)*32768 + \
        (nt_)*2048 + ((kh_) ? bB1 : bB0)))

__global__ __launch_bounds__(512)
void gemm_bf16_8ph(const unsigned short* __restrict__ Xb,
                   const unsigned short* __restrict__ Wb,
                   const float* __restrict__ scale,
                   const float* __restrict__ bias,
                   float* __restrict__ Out) {
    __shared__ unsigned short As[2 * 2 * 128 * 64];  // 64 KiB
    __shared__ unsigned short Bs[2 * 2 * 128 * 64];  // 64 KiB

    const int tid  = threadIdx.x;
    const int lane = tid & 63;
    const int wave = tid >> 6;       // 0..7
    const int wm   = wave >> 2;      // 0..1  (M half)
    const int wn   = wave & 3;       // 0..3  (N quarter)
    const int quad = lane >> 4;
    const int l16  = lane & 15;
    const int lr   = lane >> 3;      // staging row-in-group
    const int cc   = (lane & 7) ^ lr;  // pre-swizzled source chunk

    // XCD-aware swizzle: 512 blocks, 8 XCDs, 64 consecutive per XCD
    int lid = blockIdx.y * 16 + blockIdx.x;
    lid = (lid & 7) * 64 + (lid >> 3);
    const int n0 = (lid & 15) << 8;  // 16 N-tiles
    const int m0 = (lid >> 4) << 8;  // 32 M-tiles

    // staging global pointers: [half][issue]
    const unsigned short* pA[2][2];
    const unsigned short* pB[2][2];
#pragma unroll
    for (int h = 0; h < 2; ++h)
#pragma unroll
        for (int j = 0; j < 2; ++j) {
            pA[h][j] = Xb + (size_t)(m0 + h * 128 + j * 64 + wave * 8 + lr) * KDIM + cc * 8;
            pB[h][j] = Wb + (size_t)(n0 + h * 128 + j * 64 + wave * 8 + lr) * KDIM + cc * 8;
        }

    f32x4 acc[8][4];
#pragma unroll
    for (int i = 0; i < 8; ++i)
#pragma unroll
        for (int j = 0; j < 4; ++j)
            acc[i][j] = (f32x4){0.f, 0.f, 0.f, 0.f};

    // ds_read bases: row = <const> + l16, chunk = (kh*4+quad) ^ (l16&7)
    const int aoff = l16 * 128 + ((quad ^ (l16 & 7)) << 4);
    const int aB0  = (wm << 14) + aoff;          // kh=0
    const int aB1  = aB0 ^ 64;                   // kh=1 (chunk ^4)
    const int bB0  = ((wn >> 1) << 14) + ((wn & 1) << 13) + aoff;
    const int bB1  = bB0 ^ 64;

    auto stageA = [&](int t, int h, int b) {
        char* d = (char*)As + ((b * 2 + h) << 14) + wave * 1024;
        async_load16(pA[h][0] + (size_t)t * 64, d);
        async_load16(pA[h][1] + (size_t)t * 64, d + 8192);
    };
    auto stageB = [&](int t, int h, int b) {
        char* d = (char*)Bs + ((b * 2 + h) << 14) + wave * 1024;
        async_load16(pB[h][0] + (size_t)t * 64, d);
        async_load16(pB[h][1] + (size_t)t * 64, d + 8192);
    };

    auto tile = [&](int t, int b) {
        bf16x8 bfr[4][2];
        {   // ---- phase 0: compute m-quarter 0, read all B frags ----
            bf16x8 af[2][2];
#pragma unroll
            for (int mt = 0; mt < 2; ++mt) {
                af[mt][0] = RDA(b, 0, mt, 0);
                af[mt][1] = RDA(b, 0, mt, 1);
            }
#pragma unroll
            for (int nt = 0; nt < 4; ++nt) {
                bfr[nt][0] = RDB(b, nt, 0);
                bfr[nt][1] = RDB(b, nt, 1);
            }
            if (t + 1 < NT) stageA(t + 1, 0, b ^ 1);
            BAR();
            __builtin_amdgcn_s_setprio(1);
#pragma unroll
            for (int kh = 0; kh < 2; ++kh)
#pragma unroll
                for (int mt = 0; mt < 2; ++mt)
#pragma unroll
                    for (int nt = 0; nt < 4; ++nt)
                        acc[mt][nt] = __builtin_amdgcn_mfma_f32_16x16x32_bf16(
                            af[mt][kh], bfr[nt][kh], acc[mt][nt], 0, 0, 0);
            __builtin_amdgcn_s_setprio(0);
            BAR();
        }
        {   // ---- phase 1: m-quarter 1 ----
            bf16x8 af[2][2];
#pragma unroll
            for (int mt = 0; mt < 2; ++mt) {
                af[mt][0] = RDA(b, 1, mt, 0);
                af[mt][1] = RDA(b, 1, mt, 1);
            }
            if (t + 1 < NT) stageA(t + 1, 1, b ^ 1);
            BAR();
            __builtin_amdgcn_s_setprio(1);
#pragma unroll
            for (int kh = 0; kh < 2; ++kh)
#pragma unroll
                for (int mt = 0; mt < 2; ++mt)
#pragma unroll
                    for (int nt = 0; nt < 4; ++nt)
                        acc[2 + mt][nt] = __builtin_amdgcn_mfma_f32_16x16x32_bf16(
                            af[mt][kh], bfr[nt][kh], acc[2 + mt][nt], 0, 0, 0);
            __builtin_amdgcn_s_setprio(0);
            BAR();
        }
        {   // ---- phase 2: m-quarter 2 ----
            bf16x8 af[2][2];
#pragma unroll
            for (int mt = 0; mt < 2; ++mt) {
                af[mt][0] = RDA(b, 2, mt, 0);
                af[mt][1] = RDA(b, 2, mt, 1);
            }
            if (t + 2 < NT) stageB(t + 2, 0, b);
            BAR();
            __builtin_amdgcn_s_setprio(1);
#pragma unroll
            for (int kh = 0; kh < 2; ++kh)
#pragma unroll
                for (int mt = 0; mt < 2; ++mt)
#pragma unroll
                    for (int nt = 0; nt < 4; ++nt)
                        acc[4 + mt][nt] = __builtin_amdgcn_mfma_f32_16x16x32_bf16(
                            af[mt][kh], bfr[nt][kh], acc[4 + mt][nt], 0, 0, 0);
            __builtin_amdgcn_s_setprio(0);
            BAR();
        }
        {   // ---- phase 3: m-quarter 3, counted vmcnt ----
            bf16x8 af[2][2];
#pragma unroll
            for (int mt = 0; mt < 2; ++mt) {
                af[mt][0] = RDA(b, 3, mt, 0);
                af[mt][1] = RDA(b, 3, mt, 1);
            }
            if (t + 2 < NT) stageB(t + 2, 1, b);
            if (t < NT - 2) asm volatile("s_waitcnt vmcnt(4)" ::: "memory");
            else            asm volatile("s_waitcnt vmcnt(0)" ::: "memory");
            BAR();
            __builtin_amdgcn_s_setprio(1);
#pragma unroll
            for (int kh = 0; kh < 2; ++kh)
#pragma unroll
                for (int mt = 0; mt < 2; ++mt)
#pragma unroll
                    for (int nt = 0; nt < 4; ++nt)
                        acc[6 + mt][nt] = __builtin_amdgcn_mfma_f32_16x16x32_bf16(
                            af[mt][kh], bfr[nt][kh], acc[6 + mt][nt], 0, 0, 0);
            __builtin_amdgcn_s_setprio(0);
            BAR();
        }
    };

    // prologue: tile0 (all 4 halves) + tile1 B halves; wait tile0 landed
    stageA(0, 0, 0); stageA(0, 1, 0); stageB(0, 0, 0); stageB(0, 1, 0);
    stageB(1, 0, 1); stageB(1, 1, 1);
    asm volatile("s_waitcnt vmcnt(4)" ::: "memory");
    BAR();

    for (int tt = 0; tt < NT; tt += 2) {
        tile(tt, 0);
        tile(tt + 1, 1);
    }

    // epilogue: C/D layout col = lane&15, row = quad*4 + r
#pragma unroll
    for (int nt = 0; nt < 4; ++nt) {
        const int n = n0 + wn * 64 + nt * 16 + l16;
        const float sc = scale[n];
        const float bi = bias[n];
#pragma unroll
        for (int mf = 0; mf < 8; ++mf) {
#pragma unroll
            for (int r = 0; r < 4; ++r) {
                const int m = m0 + wm * 128 + mf * 16 + quad * 4 + r;
                Out[(size_t)m * NDIM + n] = acc[mf][nt][r] * sc + bi;
            }
        }
    }
}

#undef RDA
#undef RDB

// ---------------- round-1 fused fallback (if ws too small) ----------------

#define BM 128
#define BN 128
#define BK 64
#define LDSS 72

__global__ __launch_bounds__(256, 2)
void ternary_gemm_fused(const float* __restrict__ X, const int* __restrict__ Wq,
                        const float* __restrict__ scale, const float* __restrict__ bias,
                        float* __restrict__ Out) {
    __shared__ unsigned short As[BM * LDSS];
    __shared__ unsigned short Bs[BN * LDSS];

    const int tid  = threadIdx.x;
    const int lane = tid & 63;
    const int wave = tid >> 6;
    const int quad = lane >> 4;
    const int l16  = lane & 15;
    const int wm   = (wave >> 1) * 64;
    const int wn   = (wave & 1) * 64;

    const int m0 = blockIdx.y * BM;
    const int n0 = blockIdx.x * BN;

    const int srow = tid >> 4;
    const int scol = (tid & 15) * 4;

    const float* Aptr = X  + (size_t)(m0 + srow) * KDIM + scol;
    const int*   Bptr = Wq + (size_t)(n0 + srow) * KDIM + scol;

    f32x4 acc[4][4];
#pragma unroll
    for (int i = 0; i < 4; i++)
#pragma unroll
        for (int j = 0; j < 4; j++)
            acc[i][j] = (f32x4){0.f, 0.f, 0.f, 0.f};

    for (int kt = 0; kt < KDIM; kt += BK) {
        uint2 apk[8], bpk[8];
#pragma unroll
        for (int j = 0; j < 8; j++) {
            const f32x4 av = *(const f32x4*)(Aptr + (size_t)j * 16 * KDIM + kt);
            apk[j].x = f2bf_pack(av.x, av.y);
            apk[j].y = f2bf_pack(av.z, av.w);
        }
#pragma unroll
        for (int j = 0; j < 8; j++) {
            const int4 bv = *(const int4*)(Bptr + (size_t)j * 16 * KDIM + kt);
            bpk[j].x = w2bf_pack(bv.x, bv.y);
            bpk[j].y = w2bf_pack(bv.z, bv.w);
        }
        __syncthreads();
#pragma unroll
        for (int j = 0; j < 8; j++) {
            *(uint2*)&As[(srow + j * 16) * LDSS + scol] = apk[j];
            *(uint2*)&Bs[(srow + j * 16) * LDSS + scol] = bpk[j];
        }
        __syncthreads();

#pragma unroll
        for (int h = 0; h < 2; h++) {
            bf16x8 af[4], bf[4];
#pragma unroll
            for (int mt = 0; mt < 4; mt++)
                af[mt] = *(const bf16x8*)&As[(wm + mt * 16 + l16) * LDSS + h * 32 + quad * 8];
#pragma unroll
            for (int nt = 0; nt < 4; nt++)
                bf[nt] = *(const bf16x8*)&Bs[(wn + nt * 16 + l16) * LDSS + h * 32 + quad * 8];
#pragma unroll
            for (int mt = 0; mt < 4; mt++)
#pragma unroll
                for (int nt = 0; nt < 4; nt++)
                    acc[mt][nt] = __builtin_amdgcn_mfma_f32_16x16x32_bf16(
                        af[mt], bf[nt], acc[mt][nt], 0, 0, 0);
        }
    }

#pragma unroll
    for (int nt = 0; nt < 4; nt++) {
        const int n = n0 + wn + nt * 16 + l16;
        const float sc = scale[n];
        const float bi = bias[n];
#pragma unroll
        for (int mt = 0; mt < 4; mt++) {
#pragma unroll
            for (int r = 0; r < 4; r++) {
                const int m = m0 + wm + mt * 16 + quad * 4 + r;
                Out[(size_t)m * NDIM + n] = acc[mt][nt][r] * sc + bi;
            }
        }
    }
}

extern "C" void kernel_launch(void* const* d_in, const int* in_sizes, int n_in,
                              void* d_out, int out_size, void* d_ws, size_t ws_size,
                              hipStream_t stream) {
    const float* x     = (const float*)d_in[0];
    const int*   wq    = (const int*)d_in[1];
    const float* scale = (const float*)d_in[2];
    const float* bias  = (const float*)d_in[3];
    float* out = (float*)d_out;

    const size_t xb_bytes = (size_t)MDIM * KDIM * 2;  // 64 MiB
    const size_t wb_bytes = (size_t)NDIM * KDIM * 2;  // 32 MiB

    if (ws_size >= xb_bytes + wb_bytes) {
        unsigned short* Xb = (unsigned short*)d_ws;
        unsigned short* Wb = (unsigned short*)((char*)d_ws + xb_bytes);

        convert_all<<<CVT_BLOCKS, 256, 0, stream>>>(x, wq, (uint2*)Xb, (uint2*)Wb);

        dim3 grid(NDIM / 256, MDIM / 256);  // (16, 32)
        gemm_bf16_8ph<<<grid, dim3(512), 0, stream>>>(Xb, Wb, scale, bias, out);
    } else {
        dim3 grid(NDIM / BN, MDIM / BM);
        ternary_gemm_fused<<<grid, dim3(256), 0, stream>>>(x, wq, scale, bias, out);
    }
}